// Round 12
// baseline (1817.167 us; speedup 1.0000x reference)
//
#include <hip/hip_runtime.h>
#include <hip/hip_bf16.h>

typedef unsigned short ushort_t;
typedef __attribute__((ext_vector_type(8))) short bf16x8_t;   // 8 bf16 in 4 VGPRs
typedef __attribute__((ext_vector_type(4))) short bf16x4_t;   // 4 bf16
typedef __attribute__((ext_vector_type(4))) float f32x4_t;

#define NPIX 16384      // 128*128
#define CCH 512

__device__ __forceinline__ float bf2f(unsigned short u){
    union { unsigned int i; float f; } v; v.i = ((unsigned int)u) << 16; return v.f;
}
__device__ __forceinline__ unsigned short f2bf(float f){
    unsigned int x = __float_as_uint(f);
    x += 0x7fffu + ((x >> 16) & 1u);          // RNE
    return (unsigned short)(x >> 16);
}
// load one scalar from an external tensor whose dtype is flag-determined
__device__ __forceinline__ float ldE(const void* p, size_t i, int f32){
    return f32 ? ((const float*)p)[i] : bf2f(((const ushort_t*)p)[i]);
}

// ---------------- dtype detector: bf16-view of wq has huge/NaN elements iff data is fp32 ----------------
__global__ __launch_bounds__(256) void k_detect(const ushort_t* __restrict__ wq, int* __restrict__ flag){
    int t = threadIdx.x;
    int bad = 0;
    for (int i = t; i < 8192; i += 256){
        unsigned int e = (wq[i] >> 7) & 0xFFu;   // bf16 exponent field
        if (e >= 128u) bad = 1;                  // |v| >= 2.0 (or inf/nan): impossible for 0.02*N(0,1)
    }
    if (bad) atomicOr(flag, 1);
}

// ---------------- tiny kernels: cdp = prior @ w1 @ w2 ----------------
__global__ __launch_bounds__(256) void k_prior1(const void* __restrict__ prior,
                                                const void* __restrict__ w1,
                                                const int* __restrict__ flagp,
                                                float* __restrict__ tmp){
    int f32 = *flagp;
    int b = blockIdx.y;
    int m = blockIdx.x*256 + threadIdx.x;     // 0..2047
    float acc = 0.f;
    if (f32){
        const float* P = (const float*)prior; const float* W = (const float*)w1;
        #pragma unroll 8
        for (int k = 0; k < 512; ++k) acc += P[b*512 + k] * W[(size_t)k*2048 + m];
    } else {
        const ushort_t* P = (const ushort_t*)prior; const ushort_t* W = (const ushort_t*)w1;
        #pragma unroll 8
        for (int k = 0; k < 512; ++k) acc += bf2f(P[b*512 + k]) * bf2f(W[(size_t)k*2048 + m]);
    }
    tmp[b*2048 + m] = acc;
}

__global__ __launch_bounds__(256) void k_cdp(const float* __restrict__ tmp,
                                             const void* __restrict__ w2,
                                             const int* __restrict__ flagp,
                                             float* __restrict__ cdp){
    int f32 = *flagp;
    int b = blockIdx.y;
    int j = blockIdx.x*256 + threadIdx.x;     // 0..1023
    float acc = 0.f;
    if (f32){
        const float* W = (const float*)w2;
        #pragma unroll 8
        for (int m = 0; m < 2048; ++m) acc += tmp[b*2048 + m] * W[(size_t)m*1024 + j];
    } else {
        const ushort_t* W = (const ushort_t*)w2;
        #pragma unroll 8
        for (int m = 0; m < 2048; ++m) acc += tmp[b*2048 + m] * bf2f(W[(size_t)m*1024 + j]);
    }
    cdp[b*1024 + j] = acc;
}

// ---------------- transpose wproj (512x512) -> wprojT (bf16 internal) ----------------
__global__ __launch_bounds__(256) void k_transpose(const void* __restrict__ wproj,
                                                   const int* __restrict__ flagp,
                                                   ushort_t* __restrict__ wprojT){
    __shared__ ushort_t T[64*72];
    int f32 = *flagp;
    int t = threadIdx.x;
    int ot = blockIdx.x, ct = blockIdx.y;
    #pragma unroll
    for (int p = 0; p < 16; ++p){
        int cl = p*4 + (t>>6);
        int ol = t & 63;
        float w = ldE(wproj, (size_t)(ct*64 + cl)*512 + ot*64 + ol, f32);
        T[ol*72 + cl] = f2bf(w);
    }
    __syncthreads();
    int ol = t >> 2, cq = (t & 3)*16;
    #pragma unroll
    for (int e = 0; e < 16; ++e)
        wprojT[(size_t)(ot*64 + ol)*512 + ct*64 + cq + e] = T[ol*72 + cq + e];
}

// -------- build per-batch scaled QKV weights (transposed, bf16) + t@W bias --------
__global__ __launch_bounds__(256) void k_wqkv(const void* __restrict__ wq,
                                              const void* __restrict__ wk,
                                              const void* __restrict__ wv,
                                              const int* __restrict__ flagp,
                                              const float* __restrict__ cdp,
                                              ushort_t* __restrict__ WT,
                                              float* __restrict__ tb){
    __shared__ ushort_t T[64*72];
    int f32 = *flagp;
    int t = threadIdx.x;
    int kt = blockIdx.x, jt = blockIdx.y, b = blockIdx.z;   // kt<8, jt<24
    const void* W = (jt < 8) ? wq : ((jt < 16) ? wk : wv);
    int jcol0 = (jt & 7) * 64;
    int jl = t & 63;
    float tbacc = 0.f;
    #pragma unroll
    for (int p = 0; p < 16; ++p){
        int kl = p*4 + (t>>6);
        int k  = kt*64 + kl;
        float wf = ldE(W, (size_t)k*512 + jcol0 + jl, f32);
        T[jl*72 + kl] = f2bf(cdp[b*1024 + k] * wf);
        tbacc += cdp[b*1024 + 512 + k] * wf;
    }
    atomicAdd(&tb[b*1536 + jt*64 + jl], tbacc);
    __syncthreads();
    int jl2 = t >> 2, cq = (t & 3)*16;
    #pragma unroll
    for (int e = 0; e < 16; ++e)
        WT[((size_t)b*1536 + jt*64 + jl2)*512 + kt*64 + cq + e] = T[jl2*72 + cq + e];
}

// ---------------- X transpose: x (b,16384,512) -> XT (b,512,16384) bf16 + column sums ----------------
__global__ __launch_bounds__(256) void k_xt(const void* __restrict__ x,
                                            const int* __restrict__ flagp,
                                            ushort_t* __restrict__ XT,
                                            float* __restrict__ xs){
    __shared__ ushort_t T[64*66];
    int f32 = *flagp;
    int t = threadIdx.x;
    int nt = blockIdx.x, ct = blockIdx.y, b = blockIdx.z;
    int n0 = nt*64, c0 = ct*64;
    int r = t >> 2, cs = (t & 3)*16;
    size_t ibase = ((size_t)b*NPIX + n0 + r)*CCH + c0 + cs;
    if (f32){
        const float* xp = (const float*)x + ibase;
        #pragma unroll
        for (int e4 = 0; e4 < 4; ++e4){
            float4 v = ((const float4*)xp)[e4];
            T[r*66 + cs + e4*4 + 0] = f2bf(v.x);
            T[r*66 + cs + e4*4 + 1] = f2bf(v.y);
            T[r*66 + cs + e4*4 + 2] = f2bf(v.z);
            T[r*66 + cs + e4*4 + 3] = f2bf(v.w);
        }
    } else {
        const ushort_t* xp = (const ushort_t*)x + ibase;
        #pragma unroll
        for (int e8 = 0; e8 < 2; ++e8){
            bf16x8_t v = *(const bf16x8_t*)(xp + e8*8);
            #pragma unroll
            for (int e = 0; e < 8; ++e) T[r*66 + cs + e8*8 + e] = (unsigned short)(short)v[e];
        }
    }
    __syncthreads();
    int n_l = t & 63, wv = t >> 6;
    #pragma unroll
    for (int p = 0; p < 16; ++p){
        int c_l = p*4 + wv;
        unsigned short u = T[n_l*66 + c_l];
        XT[((size_t)b*512 + c0 + c_l)*16384 + n0 + n_l] = u;
        float s = bf2f(u);
        #pragma unroll
        for (int off = 32; off > 0; off >>= 1) s += __shfl_down(s, off);
        if (n_l == 0) atomicAdd(&xs[b*512 + c0 + c_l], s);
    }
}

// ---------------- V GEMM: X(b,16384,512) @ Wv'(b,512,512) -> Vraw ----------------
__global__ __launch_bounds__(256) void k_gemm_v(const void* __restrict__ X,
                                                const int* __restrict__ flagp,
                                                const ushort_t* __restrict__ WT,
                                                const float* __restrict__ tb,
                                                ushort_t* __restrict__ Vo){
    __shared__ __align__(16) ushort_t Al[128*32];
    __shared__ __align__(16) ushort_t Bl[128*32];
    const int f32 = *flagp;
    const int t = threadIdx.x;
    const int b = blockIdx.z;
    const int m0 = blockIdx.x*128, n0 = blockIdx.y*128;
    const ushort_t* Bt = WT + ((size_t)b*1536 + 1024)*CCH;   // V rows of WT
    const int lane = t & 63, wid = t >> 6;
    const int wm = (wid >> 1)*64, wn = (wid & 1)*64;
    const int quad = lane >> 4, l16 = lane & 15;
    const int srow = t >> 2, skc = (t & 3)*8;

    f32x4_t acc[4][4];
    #pragma unroll
    for (int i = 0; i < 4; ++i)
        #pragma unroll
        for (int j = 0; j < 4; ++j) acc[i][j] = (f32x4_t)0.0f;

    for (int kt = 0; kt < 16; ++kt){
        const int k0 = kt*32;
        __syncthreads();
        #pragma unroll
        for (int p = 0; p < 2; ++p){
            int row = p*64 + srow;
            if (f32){
                const float* Af = (const float*)X + (size_t)b*NPIX*CCH + (size_t)(m0+row)*CCH + k0 + skc;
                float4 a0 = ((const float4*)Af)[0], a1 = ((const float4*)Af)[1];
                bf16x8_t va;
                va[0]=(short)f2bf(a0.x); va[1]=(short)f2bf(a0.y); va[2]=(short)f2bf(a0.z); va[3]=(short)f2bf(a0.w);
                va[4]=(short)f2bf(a1.x); va[5]=(short)f2bf(a1.y); va[6]=(short)f2bf(a1.z); va[7]=(short)f2bf(a1.w);
                *(bf16x8_t*)&Al[row*32 + skc] = va;
            } else {
                const ushort_t* Ab = (const ushort_t*)X + (size_t)b*NPIX*CCH + (size_t)(m0+row)*CCH + k0 + skc;
                *(bf16x8_t*)&Al[row*32 + skc] = *(const bf16x8_t*)Ab;
            }
            *(bf16x8_t*)&Bl[row*32 + skc] = *(const bf16x8_t*)(Bt + (size_t)(n0+row)*CCH + k0 + skc);
        }
        __syncthreads();
        bf16x8_t af[4], bv[4];
        #pragma unroll
        for (int i = 0; i < 4; ++i){
            af[i] = *(const bf16x8_t*)&Al[(wm + i*16 + l16)*32 + quad*8];
            bv[i] = *(const bf16x8_t*)&Bl[(wn + i*16 + l16)*32 + quad*8];
        }
        #pragma unroll
        for (int i = 0; i < 4; ++i)
            #pragma unroll
            for (int j = 0; j < 4; ++j)
                acc[i][j] = __builtin_amdgcn_mfma_f32_16x16x32_bf16(af[i], bv[j], acc[i][j], 0, 0, 0);
    }

    #pragma unroll
    for (int j = 0; j < 4; ++j){
        const int c = n0 + wn + j*16 + l16;                 // 0..511
        const float tbv = tb[b*1536 + 1024 + c];
        #pragma unroll
        for (int i = 0; i < 4; ++i){
            const int mr = m0 + wm + i*16 + quad*4;
            #pragma unroll
            for (int r = 0; r < 4; ++r){
                const size_t idx = ((size_t)b*NPIX + mr + r)*CCH + c;
                Vo[idx] = f2bf(acc[i][j][r] + tbv);
            }
        }
    }
}

// ---------------- Gx partials: XT(b,512,16384) x XT^T -> Gxp[ns] (MFMA, no LDS) ----------------
__global__ __launch_bounds__(256) void k_gx(const ushort_t* __restrict__ XT,
                                            float* __restrict__ Gxp){
    const int t = threadIdx.x;
    const int kt = blockIdx.x, lt = blockIdx.y;
    const int b = blockIdx.z >> 2, ns = blockIdx.z & 3;
    const int lane = t & 63, wid = t >> 6;
    const int wm = (wid >> 1)*64, wn = (wid & 1)*64;
    const int quad = lane >> 4, l16 = lane & 15;
    const ushort_t* Abase = XT + ((size_t)(b*512 + kt*128 + wm + l16))*16384 + quad*8;
    const ushort_t* Bbase = XT + ((size_t)(b*512 + lt*128 + wn + l16))*16384 + quad*8;

    f32x4_t acc[4][4];
    #pragma unroll
    for (int i = 0; i < 4; ++i)
        #pragma unroll
        for (int j = 0; j < 4; ++j) acc[i][j] = (f32x4_t)0.0f;

    const int nb0 = ns*4096;
    for (int it = 0; it < 128; ++it){
        const int nb = nb0 + it*32;
        bf16x8_t af[4], bv[4];
        #pragma unroll
        for (int i = 0; i < 4; ++i){
            af[i] = *(const bf16x8_t*)(Abase + (size_t)i*16*16384 + nb);
            bv[i] = *(const bf16x8_t*)(Bbase + (size_t)i*16*16384 + nb);
        }
        #pragma unroll
        for (int i = 0; i < 4; ++i)
            #pragma unroll
            for (int j = 0; j < 4; ++j)
                acc[i][j] = __builtin_amdgcn_mfma_f32_16x16x32_bf16(af[i], bv[j], acc[i][j], 0, 0, 0);
    }

    float* Gg = Gxp + (size_t)(ns*4 + b)*262144;
    #pragma unroll
    for (int j = 0; j < 4; ++j){
        const int c = lt*128 + wn + j*16 + l16;
        #pragma unroll
        for (int i = 0; i < 4; ++i){
            const int mr = kt*128 + wm + i*16 + quad*4;
            #pragma unroll
            for (int r = 0; r < 4; ++r)
                Gg[(size_t)(mr + r)*512 + c] = acc[i][j][r];
        }
    }
}

// ---------------- reduce Gx partials ----------------
__global__ __launch_bounds__(256) void k_gxr(const float* __restrict__ Gxp,
                                             float* __restrict__ Gx){
    size_t i = ((size_t)blockIdx.x*256 + threadIdx.x)*4;   // over 4*512*512 floats
    float4 s = *(const float4*)(Gxp + i);
    #pragma unroll
    for (int ns = 1; ns < 4; ++ns){
        float4 v = *(const float4*)(Gxp + (size_t)ns*1048576 + i);
        s.x += v.x; s.y += v.y; s.z += v.z; s.w += v.w;
    }
    *(float4*)(Gx + i) = s;
}

// ---------------- M = W(Q,K) * Gx : MT[b][jall][k] = sum_l WT[b][jall][l]*Gx[b][l][k] ----------------
__global__ __launch_bounds__(256) void k_m(const float* __restrict__ Gx,
                                           const ushort_t* __restrict__ WT,
                                           float* __restrict__ MT){
    int t = threadIdx.x;
    int kt = blockIdx.x;      // 0..7, 64 k each
    int jt = blockIdx.y;      // 0..15, 64 j each (Q rows then K rows of WT)
    int b  = blockIdx.z;
    int j_l = t & 63, kq = t >> 6;           // kq 0..3 -> 16 k each
    int jall = jt*64 + j_l;                  // 0..1023
    int k0 = kt*64 + kq*16;
    const ushort_t* wrow = WT + ((size_t)b*1536 + jall)*512;
    const float* gbase = Gx + (size_t)b*512*512 + k0;
    float acc[16] = {};
    #pragma unroll 2
    for (int l = 0; l < 512; ++l){
        float w = bf2f(wrow[l]);
        const float4* g4 = (const float4*)(gbase + (size_t)l*512);
        #pragma unroll
        for (int m4 = 0; m4 < 4; ++m4){
            float4 g = g4[m4];
            acc[m4*4+0] += w*g.x; acc[m4*4+1] += w*g.y;
            acc[m4*4+2] += w*g.z; acc[m4*4+3] += w*g.w;
        }
    }
    float* out = MT + ((size_t)b*1024 + jall)*512 + k0;
    #pragma unroll
    for (int m4 = 0; m4 < 4; ++m4)
        ((float4*)out)[m4] = make_float4(acc[m4*4+0], acc[m4*4+1], acc[m4*4+2], acc[m4*4+3]);
}

// ---------------- assemble G (64x64 per b,h), nq, nk from MT, WT, xs, tb ----------------
__global__ __launch_bounds__(256) void k_g2(const float* __restrict__ MT,
                                            const ushort_t* __restrict__ WT,
                                            const float* __restrict__ xs,
                                            const float* __restrict__ tb,
                                            float* __restrict__ G,
                                            float* __restrict__ nq,
                                            float* __restrict__ nk){
    __shared__ float MQs[64][132];
    __shared__ float MKs[64][132];
    __shared__ ushort_t WQs[64][136];
    __shared__ ushort_t WKs[64][136];
    __shared__ float xss[128];
    __shared__ float vks[64], vqs[64];
    int t = threadIdx.x;
    int h = blockIdx.x, b = blockIdx.y;
    int i = t & 63;         // G row (K index)
    int jg = t >> 6;        // wave id; j range jg*16..+16
    float acc[16] = {};
    float nrm = 0.f, vcc = 0.f;     // wave0: nk_i/vk_i ; wave1: nq_j/vq_j (j = lane)

    for (int kt = 0; kt < 4; ++kt){
        __syncthreads();
        {   // stage a 128-wide k-chunk
            int jr = t >> 2, ks = (t & 3) * 32;
            const size_t baseq = ((size_t)b*1024 + h*64 + jr)*512 + kt*128 + ks;
            const size_t basek = ((size_t)b*1024 + 512 + h*64 + jr)*512 + kt*128 + ks;
            #pragma unroll
            for (int e4 = 0; e4 < 8; ++e4){
                float4 v = *(const float4*)(MT + baseq + e4*4);
                *(float4*)&MQs[jr][ks + e4*4] = v;
                float4 w = *(const float4*)(MT + basek + e4*4);
                *(float4*)&MKs[jr][ks + e4*4] = w;
            }
            const size_t wqb = ((size_t)b*1536 + h*64 + jr)*512 + kt*128 + ks;
            const size_t wkb = ((size_t)b*1536 + 512 + h*64 + jr)*512 + kt*128 + ks;
            #pragma unroll
            for (int e8 = 0; e8 < 4; ++e8){
                *(bf16x8_t*)&WQs[jr][ks + e8*8] = *(const bf16x8_t*)(WT + wqb + e8*8);
                *(bf16x8_t*)&WKs[jr][ks + e8*8] = *(const bf16x8_t*)(WT + wkb + e8*8);
            }
            if (t < 32)
                *(float4*)&xss[t*4] = *(const float4*)(xs + b*512 + kt*128 + t*4);
        }
        __syncthreads();
        for (int k4 = 0; k4 < 128; k4 += 4){
            bf16x4_t wv4 = *(const bf16x4_t*)&WKs[i][k4];
            float wk0 = bf2f((unsigned short)wv4[0]), wk1 = bf2f((unsigned short)wv4[1]);
            float wk2 = bf2f((unsigned short)wv4[2]), wk3 = bf2f((unsigned short)wv4[3]);
            #pragma unroll
            for (int jj = 0; jj < 16; ++jj){
                float4 mq = *(const float4*)&MQs[jg*16 + jj][k4];
                acc[jj] += wk0*mq.x + wk1*mq.y + wk2*mq.z + wk3*mq.w;
            }
            float4 x4 = *(const float4*)&xss[k4];
            if (jg == 0){
                float4 mk = *(const float4*)&MKs[i][k4];
                nrm += wk0*mk.x + wk1*mk.y + wk2*mk.z + wk3*mk.w;
                vcc += wk0*x4.x + wk1*x4.y + wk2*x4.z + wk3*x4.w;
            } else if (jg == 1){
                bf16x4_t wq4 = *(const bf16x4_t*)&WQs[i][k4];
                float q0 = bf2f((unsigned short)wq4[0]), q1 = bf2f((unsigned short)wq4[1]);
                float q2 = bf2f((unsigned short)wq4[2]), q3 = bf2f((unsigned short)wq4[3]);
                float4 mq = *(const float4*)&MQs[i][k4];
                nrm += q0*mq.x + q1*mq.y + q2*mq.z + q3*mq.w;
                vcc += q0*x4.x + q1*x4.y + q2*x4.z + q3*x4.w;
            }
        }
    }
    if (jg == 0){ vks[i] = vcc; }
    if (jg == 1){ vqs[i] = vcc; }
    __syncthreads();
    float tbk_i = tb[b*1536 + 512 + h*64 + i];
    float vk_i = vks[i];
    float* Gg = G + (((size_t)b*8 + h) << 12);
    #pragma unroll
    for (int jj = 0; jj < 16; ++jj){
        int j = jg*16 + jj;
        float tbq_j = tb[b*1536 + h*64 + j];
        Gg[i*64 + j] = acc[jj] + tbq_j*vk_i + tbk_i*vqs[j] + 16384.0f*tbk_i*tbq_j;
    }
    if (jg == 0)
        nk[b*512 + h*64 + i] = nrm + 2.0f*tbk_i*vks[i] + 16384.0f*tbk_i*tbk_i;
    if (jg == 1){
        float tbq_i = tb[b*1536 + h*64 + i];
        nq[b*512 + h*64 + i] = nrm + 2.0f*tbq_i*vqs[i] + 16384.0f*tbq_i*tbq_i;
    }
}

// ------- softmax(attn) and fold into wproj: W2T[b][o][h*64+j]  (17KB LDS) -------
__global__ __launch_bounds__(256) void k_attn_w2(const float* __restrict__ G,
                                                 const float* __restrict__ nqg,
                                                 const float* __restrict__ nkg,
                                                 const void* __restrict__ rescale,
                                                 const int* __restrict__ flagp,
                                                 const ushort_t* __restrict__ wprojT,
                                                 ushort_t* __restrict__ W2T){
    __shared__ float attn[64*64];
    __shared__ float nqs[64], nks[64];
    int f32 = *flagp;
    int t = threadIdx.x;
    int h = blockIdx.x, b = blockIdx.y;
    if (t < 64){
        nqs[t] = fmaxf(sqrtf(nqg[b*512 + h*64 + t]), 1e-12f);
        nks[t] = fmaxf(sqrtf(nkg[b*512 + h*64 + t]), 1e-12f);
    }
    __syncthreads();
    if (t < 64){
        const float* Gg = G + (((size_t)b*8 + h) << 12) + t*64;
        float resc = ldE(rescale, h, f32);
        float inv_nk = resc / nks[t];
        float lv[64];
        float mx = -1e30f;
        #pragma unroll
        for (int j = 0; j < 64; ++j){ lv[j] = Gg[j]*inv_nk/nqs[j]; mx = fmaxf(mx, lv[j]); }
        float s = 0.f;
        #pragma unroll
        for (int j = 0; j < 64; ++j){ lv[j] = __expf(lv[j]-mx); s += lv[j]; }
        float inv = 1.0f/s;
        #pragma unroll
        for (int j = 0; j < 64; ++j) attn[t*64 + j] = lv[j]*inv;
    }
    __syncthreads();
    int j = t & 63, wid = t >> 6;
    float a[64];
    #pragma unroll
    for (int i = 0; i < 64; ++i) a[i] = attn[i*64 + j];
    for (int o = wid*128; o < wid*128 + 128; ++o){
        float s = 0.f;
        const bf16x8_t* wrow = (const bf16x8_t*)(wprojT + (size_t)o*512 + h*64);  // same addr across wave -> broadcast
        #pragma unroll
        for (int e8 = 0; e8 < 8; ++e8){
            bf16x8_t w8 = wrow[e8];
            #pragma unroll
            for (int e = 0; e < 8; ++e) s += a[e8*8 + e]*bf2f((unsigned short)w8[e]);
        }
        W2T[((size_t)b*512 + o)*512 + h*64 + j] = f2bf(s);
    }
}

// ---------------- depthwise 3x3 conv (SAME), optional exact GELU ----------------
__global__ __launch_bounds__(256) void k_dwconv(const ushort_t* __restrict__ in,
                                                const void* __restrict__ wgt,
                                                void* __restrict__ out,
                                                int do_gelu, int out_ext,
                                                const int* __restrict__ flagp){
    __shared__ float wlds[512*9];
    int f32 = *flagp;
    int t = threadIdx.x;
    for (int i = t; i < 4608; i += 256) wlds[i] = ldE(wgt, i, f32);
    __syncthreads();
    int c8 = (t & 63)*8;
    int sid = blockIdx.x*4 + (t >> 6);
    int xs = (sid & 7)*16;
    int y  = (sid >> 3) & 127;
    int b  = sid >> 10;
    float wr[72];
    #pragma unroll
    for (int i = 0; i < 72; ++i) wr[i] = wlds[c8*9 + i];
    const ushort_t* ib = in + (size_t)b*NPIX*CCH + c8;
    for (int xo = 0; xo < 16; ++xo){
        int x = xs + xo;
        float acc[8] = {};
        #pragma unroll
        for (int ky = 0; ky < 3; ++ky){
            int yy = y + ky - 1;
            if ((unsigned)yy >= 128u) continue;
            #pragma unroll
            for (int kx = 0; kx < 3; ++kx){
                int xx = x + kx - 1;
                if ((unsigned)xx >= 128u) continue;
                bf16x8_t v = *(const bf16x8_t*)(ib + (size_t)(yy*128 + xx)*CCH);
                #pragma unroll
                for (int j2 = 0; j2 < 8; ++j2)
                    acc[j2] += bf2f((unsigned short)v[j2]) * wr[j2*9 + ky*3 + kx];
            }
        }
        size_t eidx = ((size_t)b*NPIX + y*128 + x)*CCH + c8;
        if (do_gelu){
            #pragma unroll
            for (int j2 = 0; j2 < 8; ++j2) acc[j2] = 0.5f*acc[j2]*(1.0f + erff(acc[j2]*0.70710678118654752f));
        }
        if (out_ext && f32){
            float* of = (float*)out + eidx;
            float4 r0, r1;
            r0.x=acc[0]; r0.y=acc[1]; r0.z=acc[2]; r0.w=acc[3];
            r1.x=acc[4]; r1.y=acc[5]; r1.z=acc[6]; r1.w=acc[7];
            ((float4*)of)[0] = r0; ((float4*)of)[1] = r1;
        } else {
            bf16x8_t r;
            #pragma unroll
            for (int j2 = 0; j2 < 8; ++j2) r[j2] = (short)f2bf(acc[j2]);
            *(bf16x8_t*)((ushort_t*)out + eidx) = r;
        }
    }
}

// ---------------- Vraw *= illu (in place, elementwise) ----------------
__global__ __launch_bounds__(256) void k_villu(ushort_t* __restrict__ V,
                                               const void* __restrict__ illu,
                                               const int* __restrict__ flagp){
    int f32 = *flagp;
    size_t idx = ((size_t)blockIdx.x*256 + threadIdx.x)*8;
    bf16x8_t v = *(bf16x8_t*)(V + idx);
    float il[8];
    if (f32){
        const float* ip = (const float*)illu + idx;
        float4 a = ((const float4*)ip)[0], b4 = ((const float4*)ip)[1];
        il[0]=a.x; il[1]=a.y; il[2]=a.z; il[3]=a.w;
        il[4]=b4.x; il[5]=b4.y; il[6]=b4.z; il[7]=b4.w;
    } else {
        bf16x8_t iv = *(const bf16x8_t*)((const ushort_t*)illu + idx);
        #pragma unroll
        for (int e = 0; e < 8; ++e) il[e] = bf2f((unsigned short)iv[e]);
    }
    bf16x8_t r;
    #pragma unroll
    for (int e = 0; e < 8; ++e) r[e] = (short)f2bf(bf2f((unsigned short)v[e]) * il[e]);
    *(bf16x8_t*)(V + idx) = r;
}

// ------------- final GEMM: Villu(b,16384,512) @ W2(b,512,512) + bproj + pe -------------
__global__ __launch_bounds__(256) void k_gemm_out(const ushort_t* __restrict__ Villu,
                                                  const int* __restrict__ flagp,
                                                  const ushort_t* __restrict__ W2T,
                                                  const void* __restrict__ bproj,
                                                  void* __restrict__ dout){
    __shared__ __align__(16) ushort_t Al[128*32];
    __shared__ __align__(16) ushort_t Bl[128*32];
    const int f32 = *flagp;
    const int t = threadIdx.x;
    const int b = blockIdx.z;
    const int m0 = blockIdx.x*128, n0 = blockIdx.y*128;
    const ushort_t* A  = Villu + (size_t)b*NPIX*CCH;
    const ushort_t* Bt = W2T + (size_t)b*512*512;
    const int lane = t & 63, wid = t >> 6;
    const int wm = (wid >> 1)*64, wn = (wid & 1)*64;
    const int quad = lane >> 4, l16 = lane & 15;
    const int srow = t >> 2, skc = (t & 3)*8;

    f32x4_t acc[4][4];
    #pragma unroll
    for (int i = 0; i < 4; ++i)
        #pragma unroll
        for (int j = 0; j < 4; ++j) acc[i][j] = (f32x4_t)0.0f;

    for (int kt = 0; kt < 16; ++kt){
        const int k0 = kt*32;
        __syncthreads();
        #pragma unroll
        for (int p = 0; p < 2; ++p){
            int row = p*64 + srow;
            size_t aidx = (size_t)(m0+row)*CCH + k0 + skc;
            *(bf16x8_t*)&Al[row*32 + skc] = *(const bf16x8_t*)(A + aidx);
            *(bf16x8_t*)&Bl[row*32 + skc] = *(const bf16x8_t*)(Bt + (size_t)(n0+row)*CCH + k0 + skc);
        }
        __syncthreads();
        bf16x8_t af[4], bv[4];
        #pragma unroll
        for (int i = 0; i < 4; ++i){
            af[i] = *(const bf16x8_t*)&Al[(wm + i*16 + l16)*32 + quad*8];
            bv[i] = *(const bf16x8_t*)&Bl[(wn + i*16 + l16)*32 + quad*8];
        }
        #pragma unroll
        for (int i = 0; i < 4; ++i)
            #pragma unroll
            for (int j = 0; j < 4; ++j)
                acc[i][j] = __builtin_amdgcn_mfma_f32_16x16x32_bf16(af[i], bv[j], acc[i][j], 0, 0, 0);
    }

    #pragma unroll
    for (int j = 0; j < 4; ++j){
        const int c = n0 + wn + j*16 + l16;
        const float bp = ldE(bproj, c, f32);
        #pragma unroll
        for (int i = 0; i < 4; ++i){
            const int mr = m0 + wm + i*16 + quad*4;
            #pragma unroll
            for (int r = 0; r < 4; ++r){
                const size_t idx = ((size_t)b*NPIX + mr + r)*CCH + c;
                float pe = f32 ? ((const float*)dout)[idx] : bf2f(((const ushort_t*)dout)[idx]);
                float v = acc[i][j][r] + bp + pe;
                if (f32) ((float*)dout)[idx] = v;
                else     ((ushort_t*)dout)[idx] = f2bf(v);
            }
        }
    }
}

extern "C" void kernel_launch(void* const* d_in, const int* in_sizes, int n_in,
                              void* d_out, int out_size, void* d_ws, size_t ws_size,
                              hipStream_t stream){
    const void* x_in    = d_in[0];
    const void* illu    = d_in[1];
    const void* prior   = d_in[2];
    const void* wq      = d_in[3];
    const void* wk      = d_in[4];
    const void* wv      = d_in[5];
    const void* rescale = d_in[6];
    const void* wproj   = d_in[7];
    const void* bproj   = d_in[8];
    const void* cw1     = d_in[9];
    const void* cw2     = d_in[10];
    const void* pw1     = d_in[11];
    const void* pw2     = d_in[12];
    char* ws = (char*)d_ws;

    int*      flag = (int*)(ws + 0);             // 256 B
    float*    tb   = (float*)(ws + 256);         // 24576  (atomic -> zero)
    float*    xs   = (float*)(ws + 24832);       // 8192   (atomic -> zero)  [zero region ends 33024]
    float*    cdp  = (float*)(ws + 33024);       // 16384
    float*    tmp  = (float*)(ws + 49408);       // 32768
    ushort_t* wpT  = (ushort_t*)(ws + 82176);    // 524288
    ushort_t* WT   = (ushort_t*)(ws + 606464);   // 6291456
    float*    Gxp  = (float*)(ws + 6897920);     // 16777216 (4 partials)
    float*    Gx   = (float*)(ws + 23675136);    // 4194304
    float*    MT   = (float*)(ws + 27869440);    // 8388608
    ushort_t* W2T  = (ushort_t*)(ws + 36258048); // 2097152
    float*    G    = (float*)(ws + 38355200);    // 524288
    float*    nq   = (float*)(ws + 38879488);    // 8192
    float*    nk   = (float*)(ws + 38887680);    // 8192
    ushort_t* XT   = (ushort_t*)(ws + 38895872); // 67108864 ; dead after k_gx -> reused as conv intermediate d1
    ushort_t* Vraw = (ushort_t*)(ws + 106004736);// 67108864 ; overwritten in place by V*illu after dwconv1
    ushort_t* d1   = XT;                         // total ~165 MB (< previous 210.9 MB proven footprint)

    hipMemsetAsync(ws, 0, 33024, stream);
    k_detect   <<<dim3(1),       256, 0, stream>>>((const ushort_t*)wq, flag);
    k_prior1   <<<dim3(8,4),     256, 0, stream>>>(prior, cw1, flag, tmp);
    k_cdp      <<<dim3(4,4),     256, 0, stream>>>(tmp, cw2, flag, cdp);
    k_transpose<<<dim3(8,8),     256, 0, stream>>>(wproj, flag, wpT);
    k_wqkv     <<<dim3(8,24,4),  256, 0, stream>>>(wq, wk, wv, flag, cdp, WT, tb);
    k_xt       <<<dim3(256,8,4), 256, 0, stream>>>(x_in, flag, XT, xs);
    k_gemm_v   <<<dim3(128,4,4), 256, 0, stream>>>(x_in, flag, WT, tb, Vraw);
    k_gx       <<<dim3(4,4,16),  256, 0, stream>>>(XT, Gxp);
    k_gxr      <<<dim3(1024),    256, 0, stream>>>(Gxp, Gx);
    k_m        <<<dim3(8,16,4),  256, 0, stream>>>(Gx, WT, MT);
    k_g2       <<<dim3(8,4),     256, 0, stream>>>(MT, WT, xs, tb, G, nq, nk);
    k_attn_w2  <<<dim3(8,4),     256, 0, stream>>>(G, nq, nk, rescale, flag, wpT, W2T);
    k_dwconv   <<<dim3(1024),    256, 0, stream>>>(Vraw, pw1, d1, 1, 0, flag);
    k_villu    <<<dim3(16384),   256, 0, stream>>>(Vraw, illu, flag);
    k_dwconv   <<<dim3(1024),    256, 0, stream>>>(d1, pw2, d_out, 0, 1, flag);
    k_gemm_out <<<dim3(128,4,4), 256, 0, stream>>>(Vraw, flag, W2T, bproj, d_out);
}